// Round 8
// baseline (66.766 us; speedup 1.0000x reference)
//
#include <hip/hip_runtime.h>
#include <math.h>

#define HW     262144   // 512*512
#define WIDTH  512
#define BB     4
#define NN     32
#define KK     256
#define PP     8192
#define EPSF   1e-4f
#define ONE_M_EPS (1.0f - 1e-4f)

// ---- block partition: inst first (longest), small families fill the tail ----
#define NBLK_INST  1024  // 8 (b,g) x 128 blocks; 8 items x 64 float4 each
#define NBLK_WH    256
#define NBLK_FOCAL 512   // 2 tensors x 256
#define NBLK_TAN   32
#define NBLK_VAR   128
#define OFF_WH     NBLK_INST
#define OFF_FOCAL  (OFF_WH + NBLK_WH)
#define OFF_TAN    (OFF_FOCAL + NBLK_FOCAL)
#define OFF_VAR    (OFF_TAN + NBLK_TAN)
#define NBLK_TOTAL (OFF_VAR + NBLK_VAR)   // 1952

// ---- workspace layout (floats) ----
#define WS_INST  0       // [8 bg][128 blk][32]  (il*2 + {sum,cnt}) = 32768
#define WS_FOCAL 32768   // [2][256][2] = 1024
#define WS_WH    33792   // [256][2]    = 512
#define WS_TAN   34304   // [32]
#define WS_VAR   34336   // [128]

__device__ __forceinline__ float ftanh(float x) {
    float e = __expf(2.0f * x);
    return 1.0f - 2.0f / (e + 1.0f);
}

__device__ __forceinline__ float wave_reduce(float v) {
    #pragma unroll
    for (int off = 1; off < 64; off <<= 1) v += __shfl_xor(v, off, 64);
    return v;
}

__device__ __forceinline__ float block_reduce(float v, float* sbuf) {
    v = wave_reduce(v);
    int lane = threadIdx.x & 63, wid = threadIdx.x >> 6;
    __syncthreads();
    if (lane == 0) sbuf[wid] = v;
    __syncthreads();
    float r = 0.f;
    if (threadIdx.x == 0) {
        for (int i = 0; i < 4; ++i) r += sbuf[i];
    }
    return r;
}

// barrier that does NOT drain vmcnt: LDS ordering only. In-flight global
// loads (targeting private registers) legally cross it.
__device__ __forceinline__ void wg_barrier() {
    asm volatile("s_waitcnt lgkmcnt(0)" ::: "memory");
    __builtin_amdgcn_s_barrier();
}

// ---- AE instance focal: LDS double-buffered masks + reg double-buffered ae,
// prefetches survive barriers (raw s_barrier, counted waits stay on vmcnt). ----
// idx in [0,1024): bg = idx>>7 (b=bg>>1, g=bg&1), blk = idx&127.
// Block: 16 instances x 512 float4 (8 items of 64 f4 = 256 px each).
// Wave qi owns instances qi*4..qi*4+3; lane = f4 within item.
__device__ __forceinline__ void inst_part(int idx, const float* __restrict__ ae,
                                          const float* __restrict__ masks,
                                          const int* __restrict__ centers,
                                          float* __restrict__ ws,
                                          float4* __restrict__ s_mask,  // [2][16][64]
                                          float* __restrict__ s_cyx) {  // [32]
    const int tid = threadIdx.x, lane = tid & 63, qi = tid >> 6;
    const int bg = idx >> 7, blk = idx & 127;
    const int b = bg >> 1, g = bg & 1;
    if (tid < 16) {
        int cb = (b * NN + g * 16 + tid) * 2;
        s_cyx[tid]      = centers[cb]     * (1.0f / 512.0f);
        s_cyx[16 + tid] = centers[cb + 1] * (1.0f / 512.0f);
    }
    __syncthreads();
    float cy[4], cx[4];
    #pragma unroll
    for (int i = 0; i < 4; ++i) {
        cy[i] = s_cyx[qi * 4 + i];
        cx[i] = s_cyx[16 + qi * 4 + i];
    }

    const float4* aeb = (const float4*)ae + (size_t)b * 4 * 65536;
    const float4* mb  = (const float4*)masks + (size_t)(b * NN + g * 16) * 65536;
    const int f4base = blk * 512;   // 8 items x 64 f4

    float a_sum[4] = {0.f, 0.f, 0.f, 0.f}, a_cnt[4] = {0.f, 0.f, 0.f, 0.f};
    float4 stg0, stg1, stg2, stg3;            // mask staging (next tile)
    float4 ac0, ac1, ac2, ac3;                // ae current item
    float4 an0, an1, an2, an3;                // ae next item

#define LOADSTG(it) do { int ib_ = f4base + (it) * 64 + lane;            \
        stg0 = mb[(size_t)(0 * 4 + qi) * 65536 + ib_];                   \
        stg1 = mb[(size_t)(1 * 4 + qi) * 65536 + ib_];                   \
        stg2 = mb[(size_t)(2 * 4 + qi) * 65536 + ib_];                   \
        stg3 = mb[(size_t)(3 * 4 + qi) * 65536 + ib_]; } while (0)
#define WRITESTG(buf) do {                                               \
        s_mask[(buf) * 1024 + (0 * 4 + qi) * 64 + lane] = stg0;          \
        s_mask[(buf) * 1024 + (1 * 4 + qi) * 64 + lane] = stg1;          \
        s_mask[(buf) * 1024 + (2 * 4 + qi) * 64 + lane] = stg2;          \
        s_mask[(buf) * 1024 + (3 * 4 + qi) * 64 + lane] = stg3; } while (0)
#define LOADAE(it, r0, r1, r2, r3) do { int v_ = f4base + (it) * 64 + lane; \
        r0 = aeb[v_]; r1 = aeb[65536 + v_];                              \
        r2 = aeb[131072 + v_]; r3 = aeb[196608 + v_]; } while (0)

    LOADSTG(0);
    LOADAE(0, ac0, ac1, ac2, ac3);
    WRITESTG(0);                       // waits stg vmcnt only
    int cur = 0;
    #pragma unroll
    for (int it = 0; it < 8; ++it) {
        if (it < 7) {
            LOADSTG(it + 1);                       // in flight across barrier
            LOADAE(it + 1, an0, an1, an2, an3);    // in flight across barrier
        }
        wg_barrier();                  // LDS visible; vmcnt NOT drained
        int v = f4base + it * 64 + lane;
        int pix0 = v * 4;
        float fy  = (float)(pix0 >> 9)  * (1.0f / 512.0f);
        float fx0 = (float)(pix0 & 511) * (1.0f / 512.0f);
        float se0[4], se1[4], sg0[4], sg1[4];
        #pragma unroll
        for (int j = 0; j < 4; ++j) {
            se0[j] = ftanh((&ac0.x)[j]) + fy;
            se1[j] = ftanh((&ac1.x)[j]) + fx0 + (float)j * (1.0f / 512.0f);
            sg0[j] = __expf((&ac2.x)[j]);
            sg1[j] = __expf((&ac3.x)[j]);
        }
        #pragma unroll
        for (int i = 0; i < 4; ++i) {
            float4 mk = s_mask[cur * 1024 + (qi * 4 + i) * 64 + lane];
            float ccy = cy[i], ccx = cx[i];
            #pragma unroll
            for (int j = 0; j < 4; ++j) {
                float m  = (&mk.x)[j];                 // exactly 0.0 or 1.0
                float dy = se0[j] - ccy, dx = se1[j] - ccx;
                float s  = fmaf(dx * dx, sg1[j], dy * dy * sg0[j]);
                float e  = __expf(-s);
                float pc = fminf(fmaxf(e, EPSF), ONE_M_EPS);
                float omp = 1.0f - pc;
                // pos: log(pc)*omp^2 ; neg: log(omp)*pc^2 (neg_w==1, binary mask)
                // A = m ? pc : omp ; B = 1-A ; term = log(A)*B^2
                float A = (m != 0.f) ? pc : omp;
                float B = 1.0f - A;
                a_sum[i] = fmaf(__logf(A), B * B, a_sum[i]);
                a_cnt[i] += m;
            }
        }
        if (it < 7) {
            WRITESTG(cur ^ 1);         // waits stg vmcnt (issued ~700cy ago)
            ac0 = an0; ac1 = an1; ac2 = an2; ac3 = an3;
            cur ^= 1;
        }
    }
#undef LOADSTG
#undef WRITESTG
#undef LOADAE

    // wave qi owns instances qi*4..qi*4+3: pure in-wave reduction
    #pragma unroll
    for (int i = 0; i < 4; ++i) {
        float v0 = wave_reduce(a_sum[i]);
        float v1 = wave_reduce(a_cnt[i]);
        if (lane == 0) {
            int il = qi * 4 + i;
            ws[WS_INST + (bg * 128 + blk) * 32 + il * 2 + 0] = v0;
            ws[WS_INST + (bg * 128 + blk) * 32 + il * 2 + 1] = v1;
        }
    }
}

// ---- cls/kp focal: idx = t*256 + blk, 4 iters ----
__device__ __forceinline__ void focal_part(int idx, const float* __restrict__ cls_out,
                                           const float* __restrict__ cls_mask,
                                           const float* __restrict__ kp_out,
                                           const float* __restrict__ kp_mask,
                                           float* __restrict__ ws, float* sbuf) {
    int t = idx >> 8, blk = idx & 255;
    const float4* po = (const float4*)(t == 0 ? cls_out : kp_out);
    const float4* pm = (const float4*)(t == 0 ? cls_mask : kp_mask);
    float sum = 0.f, cnt = 0.f;
    #pragma unroll
    for (int it = 0; it < 4; ++it) {
        int i = blk * 256 + threadIdx.x + it * 65536;
        float4 xo = po[i], xm = pm[i];
        #pragma unroll
        for (int j = 0; j < 4; ++j) {
            float x = (&xo.x)[j], gt = (&xm.x)[j];
            float p = 1.0f / (1.0f + __expf(-x));
            p = fminf(fmaxf(p, EPSF), ONE_M_EPS);
            float omp = 1.0f - p;
            float pos_t = __logf(p) * omp * omp;
            float og = 1.0f - gt;
            float negw = og * og; negw *= negw;
            float neg_t = __logf(omp) * p * p * negw;
            bool ispos = (gt == 1.0f);
            sum += ispos ? pos_t : neg_t;
            cnt += ispos ? 1.0f : 0.0f;
        }
    }
    float r0 = block_reduce(sum, sbuf);
    float r1 = block_reduce(cnt, sbuf);
    if (threadIdx.x == 0) {
        ws[WS_FOCAL + idx * 2 + 0] = r0;
        ws[WS_FOCAL + idx * 2 + 1] = r1;
    }
}

__device__ __forceinline__ void wh_part(int blk, const float* __restrict__ o,
                                        const float* __restrict__ tg,
                                        const float* __restrict__ m,
                                        float* __restrict__ ws, float* sbuf) {
    const float4* po  = (const float4*)o;
    const float4* pt  = (const float4*)tg;
    const float4* pmk = (const float4*)m;
    float sl = 0.f, ms = 0.f;
    #pragma unroll
    for (int it = 0; it < 8; ++it) {
        int i = blk * 256 + threadIdx.x + it * 65536;
        float4 a = po[i], b = pt[i], c = pmk[i];
        #pragma unroll
        for (int j = 0; j < 4; ++j) {
            float mm = (&c.x)[j];
            float d  = (&a.x)[j] * mm - (&b.x)[j] * mm;
            float ad = fabsf(d);
            sl += (ad < 1.0f) ? 0.5f * d * d : (ad - 0.5f);
            ms += mm;
        }
    }
    float r0 = block_reduce(sl, sbuf);
    float r1 = block_reduce(ms, sbuf);
    if (threadIdx.x == 0) {
        ws[WS_WH + blk * 2 + 0] = r0;
        ws[WS_WH + blk * 2 + 1] = r1;
    }
}

__device__ __forceinline__ void tan_part(int idx, const float* __restrict__ tan_out,
                                         const float* __restrict__ normals,
                                         const int* __restrict__ pts,
                                         float* __restrict__ ws, float* sbuf) {
    int b = idx >> 3, seg = idx & 7;
    float s = 0.f;
    for (int p = seg * 1024 + threadIdx.x; p < seg * 1024 + 1024; p += 256) {
        int base = (b * PP + p) * 2;
        int py = pts[base], px = pts[base + 1];
        int pix = py * WIDTH + px;
        float t0 = tan_out[b * 2 * HW + pix];
        float t1 = tan_out[b * 2 * HW + HW + pix];
        float inv = 1.0f / fmaxf(sqrtf(t0 * t0 + t1 * t1), EPSF);
        float n0 = normals[base], n1 = normals[base + 1];
        s += 1.0f - (n0 * t0 + n1 * t1) * inv;
    }
    float r = block_reduce(s, sbuf);
    if (threadIdx.x == 0) ws[WS_TAN + idx] = r;
}

__device__ __forceinline__ void var_part(int idx, const float* __restrict__ ae,
                                         const int* __restrict__ centers,
                                         const int* __restrict__ kps,
                                         float* __restrict__ ws, float* smem) {
    int n = idx & 31, b = idx >> 5;
    float* cy = smem, *cx = smem + 32, *sbuf = smem + 64;
    if (threadIdx.x < NN) {
        int cb = (b * NN + threadIdx.x) * 2;
        cy[threadIdx.x] = centers[cb]     * (1.0f / 512.0f);
        cx[threadIdx.x] = centers[cb + 1] * (1.0f / 512.0f);
    }
    __syncthreads();
    int k = threadIdx.x;
    int kb = ((b * NN + n) * KK + k) * 2;
    int ky = kps[kb], kx = kps[kb + 1];
    int pix = ky * WIDTH + kx;
    const float* aeb = ae + (size_t)b * 4 * HW;
    float se0 = ftanh(aeb[pix])      + ky * (1.0f / 512.0f);
    float se1 = ftanh(aeb[HW + pix]) + kx * (1.0f / 512.0f);
    float sg0 = __expf(aeb[2 * HW + pix]);
    float sg1 = __expf(aeb[3 * HW + pix]);
    float own = 0.f, mx = -1e30f;
    #pragma unroll
    for (int m = 0; m < NN; ++m) {
        float d0 = se0 - cy[m], d1 = se1 - cx[m];
        float dist = __expf(-(d0 * d0 * sg0 + d1 * d1 * sg1));
        mx = fmaxf(mx, dist);
        if (m == n) own = dist;
    }
    float r = block_reduce(fabsf(own - mx), sbuf);
    if (threadIdx.x == 0) ws[WS_VAR + b * NN + n] = r;
}

// ---- the mega kernel: one dispatch for all partials ----
__global__ void __launch_bounds__(256, 2)
k_mega(const float* __restrict__ cls_out, const float* __restrict__ wh_out,
       const float* __restrict__ kp_out,  const float* __restrict__ ae_out,
       const float* __restrict__ tan_out, const float* __restrict__ cls_mask,
       const float* __restrict__ wh_target, const float* __restrict__ wh_mask,
       const float* __restrict__ kp_mask, const float* __restrict__ ae_masks,
       const float* __restrict__ tan_normals,
       const int* __restrict__ centers, const int* __restrict__ kps,
       const int* __restrict__ tan_points, float* __restrict__ ws) {
    __shared__ float4 s_mask[2 * 16 * 64];   // 32 KB double-buffered mask tiles
    __shared__ float  s_cyx[32];
    int bid = blockIdx.x;
    if (bid < NBLK_INST) {
        inst_part(bid, ae_out, ae_masks, centers, ws, s_mask, s_cyx);
    } else if (bid < OFF_FOCAL) {
        wh_part(bid - OFF_WH, wh_out, wh_target, wh_mask, ws, (float*)s_mask);
    } else if (bid < OFF_TAN) {
        focal_part(bid - OFF_FOCAL, cls_out, cls_mask, kp_out, kp_mask, ws, (float*)s_mask);
    } else if (bid < OFF_VAR) {
        tan_part(bid - OFF_TAN, tan_out, tan_normals, tan_points, ws, (float*)s_mask);
    } else {
        var_part(bid - OFF_VAR, ae_out, centers, kps, ws, (float*)s_mask);
    }
}

// ---- finalize: 1 block ----
__global__ void __launch_bounds__(256)
k_final(const float* __restrict__ ws, float* __restrict__ out) {
    __shared__ float sbuf[4];
    int tid = threadIdx.x;
    float ae_v = 0.f;
    if (tid < 128) {   // tid = b*32 + n
        int b = tid >> 5, n = tid & 31, g = n >> 4, il = n & 15;
        const float* base = ws + WS_INST + (b * 2 + g) * 128 * 32 + il * 2;
        float sum = 0.f, cnt = 0.f;
        #pragma unroll 8
        for (int k = 0; k < 128; ++k) { sum += base[k * 32]; cnt += base[k * 32 + 1]; }
        // where(np>0, -(pos+neg)/max(np,1), -neg) == -sum/max(np,1)  (np==0 => pos==0)
        ae_v = -sum / fmaxf(cnt, 1.0f) + ws[WS_VAR + tid];
    }
    float ae_sum = block_reduce(ae_v, sbuf);

    float cls_sum = block_reduce(ws[WS_FOCAL + tid * 2], sbuf);
    float cls_cnt = block_reduce(ws[WS_FOCAL + tid * 2 + 1], sbuf);
    float kp_sum  = block_reduce(ws[WS_FOCAL + 512 + tid * 2], sbuf);
    float kp_cnt  = block_reduce(ws[WS_FOCAL + 512 + tid * 2 + 1], sbuf);
    float wh_sl   = block_reduce(ws[WS_WH + tid * 2], sbuf);
    float wh_ms   = block_reduce(ws[WS_WH + tid * 2 + 1], sbuf);
    float tan_sum = block_reduce(tid < 32 ? ws[WS_TAN + tid] : 0.f, sbuf);

    if (tid == 0) {
        float l_cls = -cls_sum / fmaxf(cls_cnt, 1.0f);
        float l_kp  = -kp_sum  / fmaxf(kp_cnt,  1.0f);
        float l_wh  = 0.1f * wh_sl / (wh_ms + 1e-4f);
        float l_ae  = ae_sum / (float)(NN * BB);
        float l_tan = tan_sum / (float)(PP * BB);
        out[0] = l_cls + l_wh + l_kp + l_ae + l_tan;
    }
}

extern "C" void kernel_launch(void* const* d_in, const int* in_sizes, int n_in,
                              void* d_out, int out_size, void* d_ws, size_t ws_size,
                              hipStream_t stream) {
    const float* cls_out     = (const float*)d_in[0];
    const float* wh_out      = (const float*)d_in[1];
    const float* kp_out      = (const float*)d_in[2];
    const float* ae_out      = (const float*)d_in[3];
    const float* tan_out     = (const float*)d_in[4];
    const float* cls_mask    = (const float*)d_in[5];
    const float* wh_target   = (const float*)d_in[6];
    const float* wh_mask     = (const float*)d_in[7];
    const float* kp_mask     = (const float*)d_in[8];
    const float* ae_masks    = (const float*)d_in[9];
    const float* tan_normals = (const float*)d_in[10];
    // d_in[11] = xym: analytic (y/512, x/512)
    const int* centers    = (const int*)d_in[12];
    const int* kps        = (const int*)d_in[13];
    const int* tan_points = (const int*)d_in[14];
    float* ws  = (float*)d_ws;
    float* out = (float*)d_out;

    k_mega<<<NBLK_TOTAL, 256, 0, stream>>>(cls_out, wh_out, kp_out, ae_out, tan_out,
                                           cls_mask, wh_target, wh_mask, kp_mask,
                                           ae_masks, tan_normals, centers, kps,
                                           tan_points, ws);
    k_final<<<1, 256, 0, stream>>>(ws, out);
}

// Round 9
// 63.503 us; speedup vs baseline: 1.0514x; 1.0514x over previous
//
#include <hip/hip_runtime.h>
#include <math.h>

#define HW     262144   // 512*512
#define WIDTH  512
#define BB     4
#define NN     32
#define KK     256
#define PP     8192
#define EPSF   1e-4f
#define ONE_M_EPS (1.0f - 1e-4f)

// ---- block partition: inst first (longest), small families fill the tail ----
#define NBLK_INST  1024  // 4 b x 256 chunks; block = 1024 px, all 32 instances
#define NBLK_WH    256
#define NBLK_FOCAL 512   // 2 tensors x 256
#define NBLK_TAN   32
#define NBLK_VAR   128
#define OFF_WH     NBLK_INST
#define OFF_FOCAL  (OFF_WH + NBLK_WH)
#define OFF_TAN    (OFF_FOCAL + NBLK_FOCAL)
#define OFF_VAR    (OFF_TAN + NBLK_TAN)
#define NBLK_TOTAL (OFF_VAR + NBLK_VAR)   // 1952

// ---- workspace layout (floats) ----
#define WS_INST  0       // [1024 blocks][64]  (il*2 + {sum,cnt}) = 65536
#define WS_FOCAL 65536   // [2][256][2] = 1024
#define WS_WH    66560   // [256][2]    = 512
#define WS_TAN   67072   // [32]
#define WS_VAR   67104   // [128]
// total 67232 floats = 268,928 bytes

__device__ __forceinline__ float ftanh(float x) {
    float e = __expf(2.0f * x);
    return 1.0f - 2.0f / (e + 1.0f);
}

__device__ __forceinline__ float wave_reduce(float v) {
    #pragma unroll
    for (int off = 1; off < 64; off <<= 1) v += __shfl_xor(v, off, 64);
    return v;
}

__device__ __forceinline__ float block_reduce(float v, float* sbuf) {
    v = wave_reduce(v);
    int lane = threadIdx.x & 63, wid = threadIdx.x >> 6;
    __syncthreads();
    if (lane == 0) sbuf[wid] = v;
    __syncthreads();
    float r = 0.f;
    if (threadIdx.x == 0) {
        for (int i = 0; i < 4; ++i) r += sbuf[i];
    }
    return r;
}

// ---- AE instance focal: INSTANCE-OUTER loop ----
// idx in [0,1024): b = idx>>8, chunk = idx&255. Thread owns ONE float4 (4 px):
// v = chunk*256 + tid. se/sg computed once into 16 regs; then for il=0..31:
// one contiguous f4 mask load (single addr add), 2 accumulators, wave-reduce,
// flush to LDS row (no barrier: each wave owns its row). One barrier at end.
__device__ __forceinline__ void inst_part(int idx, const float* __restrict__ ae,
                                          const float* __restrict__ masks,
                                          const int* __restrict__ centers,
                                          float* __restrict__ ws,
                                          float* __restrict__ s_part) { // [4][64]
    const int tid = threadIdx.x, lane = tid & 63, w = tid >> 6;
    const int b = idx >> 8, chunk = idx & 255;
    const int v = chunk * 256 + tid;          // f4 index 0..65535

    // ---- per-pixel quantities, computed ONCE ----
    const float4* aeb = (const float4*)ae + (size_t)b * 4 * 65536;
    float4 a0 = aeb[v];
    float4 a1 = aeb[65536 + v];
    float4 a2 = aeb[131072 + v];
    float4 a3 = aeb[196608 + v];
    int pix0 = v * 4;
    float fy  = (float)(pix0 >> 9)  * (1.0f / 512.0f);
    float fx0 = (float)(pix0 & 511) * (1.0f / 512.0f);
    float se0[4], se1[4], sg0[4], sg1[4];
    #pragma unroll
    for (int j = 0; j < 4; ++j) {
        se0[j] = ftanh((&a0.x)[j]) + fy;
        se1[j] = ftanh((&a1.x)[j]) + fx0 + (float)j * (1.0f / 512.0f);
        sg0[j] = __expf((&a2.x)[j]);
        sg1[j] = __expf((&a3.x)[j]);
    }

    // ---- instance loop: contiguous mask stream, 2-stage pipeline ----
    const float4* mp = (const float4*)masks + ((size_t)(b * NN) << 16) + v;
    const int* cb = centers + b * NN * 2;
    float4 mk = mp[0];
    #pragma unroll 4
    for (int il = 0; il < NN; ++il) {
        float4 mk_next;
        if (il < NN - 1) mk_next = mp[(size_t)(il + 1) << 16];
        float cy = (float)cb[il * 2]     * (1.0f / 512.0f);   // uniform (SGPR)
        float cx = (float)cb[il * 2 + 1] * (1.0f / 512.0f);
        float sum = 0.f, cnt = 0.f;
        #pragma unroll
        for (int j = 0; j < 4; ++j) {
            float m  = (&mk.x)[j];                 // exactly 0.0 or 1.0
            float dy = se0[j] - cy, dx = se1[j] - cx;
            float s  = fmaf(dx * dx, sg1[j], dy * dy * sg0[j]);
            float e  = __expf(-s);
            float pc = fminf(fmaxf(e, EPSF), ONE_M_EPS);
            float omp = 1.0f - pc;
            // pos: log(pc)*omp^2 ; neg: log(omp)*pc^2 (neg_w==1, binary mask)
            float A = (m != 0.f) ? pc : omp;
            float B = 1.0f - A;
            sum = fmaf(__logf(A), B * B, sum);
            cnt += m;
        }
        float r0 = wave_reduce(sum);
        float r1 = wave_reduce(cnt);
        if (lane == 0) {
            s_part[w * 64 + il * 2 + 0] = r0;
            s_part[w * 64 + il * 2 + 1] = r1;
        }
        mk = mk_next;
    }
    __syncthreads();
    if (tid < 64) {
        float s = s_part[tid] + s_part[64 + tid] + s_part[128 + tid] + s_part[192 + tid];
        ws[WS_INST + idx * 64 + tid] = s;
    }
}

// ---- cls/kp focal: idx = t*256 + blk, 4 iters ----
__device__ __forceinline__ void focal_part(int idx, const float* __restrict__ cls_out,
                                           const float* __restrict__ cls_mask,
                                           const float* __restrict__ kp_out,
                                           const float* __restrict__ kp_mask,
                                           float* __restrict__ ws, float* sbuf) {
    int t = idx >> 8, blk = idx & 255;
    const float4* po = (const float4*)(t == 0 ? cls_out : kp_out);
    const float4* pm = (const float4*)(t == 0 ? cls_mask : kp_mask);
    float sum = 0.f, cnt = 0.f;
    #pragma unroll
    for (int it = 0; it < 4; ++it) {
        int i = blk * 256 + threadIdx.x + it * 65536;
        float4 xo = po[i], xm = pm[i];
        #pragma unroll
        for (int j = 0; j < 4; ++j) {
            float x = (&xo.x)[j], gt = (&xm.x)[j];
            float p = 1.0f / (1.0f + __expf(-x));
            p = fminf(fmaxf(p, EPSF), ONE_M_EPS);
            float omp = 1.0f - p;
            float pos_t = __logf(p) * omp * omp;
            float og = 1.0f - gt;
            float negw = og * og; negw *= negw;
            float neg_t = __logf(omp) * p * p * negw;
            bool ispos = (gt == 1.0f);
            sum += ispos ? pos_t : neg_t;
            cnt += ispos ? 1.0f : 0.0f;
        }
    }
    float r0 = block_reduce(sum, sbuf);
    float r1 = block_reduce(cnt, sbuf);
    if (threadIdx.x == 0) {
        ws[WS_FOCAL + idx * 2 + 0] = r0;
        ws[WS_FOCAL + idx * 2 + 1] = r1;
    }
}

__device__ __forceinline__ void wh_part(int blk, const float* __restrict__ o,
                                        const float* __restrict__ tg,
                                        const float* __restrict__ m,
                                        float* __restrict__ ws, float* sbuf) {
    const float4* po  = (const float4*)o;
    const float4* pt  = (const float4*)tg;
    const float4* pmk = (const float4*)m;
    float sl = 0.f, ms = 0.f;
    #pragma unroll
    for (int it = 0; it < 8; ++it) {
        int i = blk * 256 + threadIdx.x + it * 65536;
        float4 a = po[i], b = pt[i], c = pmk[i];
        #pragma unroll
        for (int j = 0; j < 4; ++j) {
            float mm = (&c.x)[j];
            float d  = (&a.x)[j] * mm - (&b.x)[j] * mm;
            float ad = fabsf(d);
            sl += (ad < 1.0f) ? 0.5f * d * d : (ad - 0.5f);
            ms += mm;
        }
    }
    float r0 = block_reduce(sl, sbuf);
    float r1 = block_reduce(ms, sbuf);
    if (threadIdx.x == 0) {
        ws[WS_WH + blk * 2 + 0] = r0;
        ws[WS_WH + blk * 2 + 1] = r1;
    }
}

__device__ __forceinline__ void tan_part(int idx, const float* __restrict__ tan_out,
                                         const float* __restrict__ normals,
                                         const int* __restrict__ pts,
                                         float* __restrict__ ws, float* sbuf) {
    int b = idx >> 3, seg = idx & 7;
    float s = 0.f;
    for (int p = seg * 1024 + threadIdx.x; p < seg * 1024 + 1024; p += 256) {
        int base = (b * PP + p) * 2;
        int py = pts[base], px = pts[base + 1];
        int pix = py * WIDTH + px;
        float t0 = tan_out[b * 2 * HW + pix];
        float t1 = tan_out[b * 2 * HW + HW + pix];
        float inv = 1.0f / fmaxf(sqrtf(t0 * t0 + t1 * t1), EPSF);
        float n0 = normals[base], n1 = normals[base + 1];
        s += 1.0f - (n0 * t0 + n1 * t1) * inv;
    }
    float r = block_reduce(s, sbuf);
    if (threadIdx.x == 0) ws[WS_TAN + idx] = r;
}

__device__ __forceinline__ void var_part(int idx, const float* __restrict__ ae,
                                         const int* __restrict__ centers,
                                         const int* __restrict__ kps,
                                         float* __restrict__ ws, float* smem) {
    int n = idx & 31, b = idx >> 5;
    float* cy = smem, *cx = smem + 32, *sbuf = smem + 64;
    if (threadIdx.x < NN) {
        int cb = (b * NN + threadIdx.x) * 2;
        cy[threadIdx.x] = centers[cb]     * (1.0f / 512.0f);
        cx[threadIdx.x] = centers[cb + 1] * (1.0f / 512.0f);
    }
    __syncthreads();
    int k = threadIdx.x;
    int kb = ((b * NN + n) * KK + k) * 2;
    int ky = kps[kb], kx = kps[kb + 1];
    int pix = ky * WIDTH + kx;
    const float* aeb = ae + (size_t)b * 4 * HW;
    float se0 = ftanh(aeb[pix])      + ky * (1.0f / 512.0f);
    float se1 = ftanh(aeb[HW + pix]) + kx * (1.0f / 512.0f);
    float sg0 = __expf(aeb[2 * HW + pix]);
    float sg1 = __expf(aeb[3 * HW + pix]);
    float own = 0.f, mx = -1e30f;
    #pragma unroll
    for (int m = 0; m < NN; ++m) {
        float d0 = se0 - cy[m], d1 = se1 - cx[m];
        float dist = __expf(-(d0 * d0 * sg0 + d1 * d1 * sg1));
        mx = fmaxf(mx, dist);
        if (m == n) own = dist;
    }
    float r = block_reduce(fabsf(own - mx), sbuf);
    if (threadIdx.x == 0) ws[WS_VAR + b * NN + n] = r;
}

// ---- the mega kernel: one dispatch for all partials ----
__global__ void __launch_bounds__(256)
k_mega(const float* __restrict__ cls_out, const float* __restrict__ wh_out,
       const float* __restrict__ kp_out,  const float* __restrict__ ae_out,
       const float* __restrict__ tan_out, const float* __restrict__ cls_mask,
       const float* __restrict__ wh_target, const float* __restrict__ wh_mask,
       const float* __restrict__ kp_mask, const float* __restrict__ ae_masks,
       const float* __restrict__ tan_normals,
       const int* __restrict__ centers, const int* __restrict__ kps,
       const int* __restrict__ tan_points, float* __restrict__ ws) {
    __shared__ float smem[256];
    int bid = blockIdx.x;
    if (bid < NBLK_INST) {
        inst_part(bid, ae_out, ae_masks, centers, ws, smem);
    } else if (bid < OFF_FOCAL) {
        wh_part(bid - OFF_WH, wh_out, wh_target, wh_mask, ws, smem);
    } else if (bid < OFF_TAN) {
        focal_part(bid - OFF_FOCAL, cls_out, cls_mask, kp_out, kp_mask, ws, smem);
    } else if (bid < OFF_VAR) {
        tan_part(bid - OFF_TAN, tan_out, tan_normals, tan_points, ws, smem);
    } else {
        var_part(bid - OFF_VAR, ae_out, centers, kps, ws, smem);
    }
}

// ---- finalize: 1 block ----
__global__ void __launch_bounds__(256)
k_final(const float* __restrict__ ws, float* __restrict__ out) {
    __shared__ float sbuf[4];
    int tid = threadIdx.x;
    float ae_v = 0.f;
    if (tid < 128) {   // tid = b*32 + il
        int b = tid >> 5, il = tid & 31;
        const float* base = ws + WS_INST + (size_t)b * 256 * 64 + il * 2;
        float sum = 0.f, cnt = 0.f;
        #pragma unroll 8
        for (int c = 0; c < 256; ++c) { sum += base[c * 64]; cnt += base[c * 64 + 1]; }
        // where(np>0, -(pos+neg)/max(np,1), -neg) == -sum/max(np,1)  (np==0 => pos==0)
        ae_v = -sum / fmaxf(cnt, 1.0f) + ws[WS_VAR + tid];
    }
    float ae_sum = block_reduce(ae_v, sbuf);

    float cls_sum = block_reduce(ws[WS_FOCAL + tid * 2], sbuf);
    float cls_cnt = block_reduce(ws[WS_FOCAL + tid * 2 + 1], sbuf);
    float kp_sum  = block_reduce(ws[WS_FOCAL + 512 + tid * 2], sbuf);
    float kp_cnt  = block_reduce(ws[WS_FOCAL + 512 + tid * 2 + 1], sbuf);
    float wh_sl   = block_reduce(ws[WS_WH + tid * 2], sbuf);
    float wh_ms   = block_reduce(ws[WS_WH + tid * 2 + 1], sbuf);
    float tan_sum = block_reduce(tid < 32 ? ws[WS_TAN + tid] : 0.f, sbuf);

    if (tid == 0) {
        float l_cls = -cls_sum / fmaxf(cls_cnt, 1.0f);
        float l_kp  = -kp_sum  / fmaxf(kp_cnt,  1.0f);
        float l_wh  = 0.1f * wh_sl / (wh_ms + 1e-4f);
        float l_ae  = ae_sum / (float)(NN * BB);
        float l_tan = tan_sum / (float)(PP * BB);
        out[0] = l_cls + l_wh + l_kp + l_ae + l_tan;
    }
}

extern "C" void kernel_launch(void* const* d_in, const int* in_sizes, int n_in,
                              void* d_out, int out_size, void* d_ws, size_t ws_size,
                              hipStream_t stream) {
    const float* cls_out     = (const float*)d_in[0];
    const float* wh_out      = (const float*)d_in[1];
    const float* kp_out      = (const float*)d_in[2];
    const float* ae_out      = (const float*)d_in[3];
    const float* tan_out     = (const float*)d_in[4];
    const float* cls_mask    = (const float*)d_in[5];
    const float* wh_target   = (const float*)d_in[6];
    const float* wh_mask     = (const float*)d_in[7];
    const float* kp_mask     = (const float*)d_in[8];
    const float* ae_masks    = (const float*)d_in[9];
    const float* tan_normals = (const float*)d_in[10];
    // d_in[11] = xym: analytic (y/512, x/512)
    const int* centers    = (const int*)d_in[12];
    const int* kps        = (const int*)d_in[13];
    const int* tan_points = (const int*)d_in[14];
    float* ws  = (float*)d_ws;
    float* out = (float*)d_out;

    k_mega<<<NBLK_TOTAL, 256, 0, stream>>>(cls_out, wh_out, kp_out, ae_out, tan_out,
                                           cls_mask, wh_target, wh_mask, kp_mask,
                                           ae_masks, tan_normals, centers, kps,
                                           tan_points, ws);
    k_final<<<1, 256, 0, stream>>>(ws, out);
}

// Round 10
// 53.620 us; speedup vs baseline: 1.2452x; 1.1843x over previous
//
#include <hip/hip_runtime.h>
#include <math.h>

#define HW     262144   // 512*512
#define WIDTH  512
#define BB     4
#define NN     32
#define KK     256
#define PP     8192
#define EPSF   1e-4f
#define ONE_M_EPS (1.0f - 1e-4f)

// ---- block partition: inst first (longest), small families fill the tail ----
#define NBLK_INST  512   // (b:4) x (grp:4 of 8 inst) x (seg:32 of 32KB plane-segment)
#define NBLK_WH    256
#define NBLK_FOCAL 512   // 2 tensors x 256
#define NBLK_TAN   32
#define NBLK_VAR   128
#define OFF_WH     NBLK_INST
#define OFF_FOCAL  (OFF_WH + NBLK_WH)
#define OFF_TAN    (OFF_FOCAL + NBLK_FOCAL)
#define OFF_VAR    (OFF_TAN + NBLK_TAN)
#define NBLK_TOTAL (OFF_VAR + NBLK_VAR)   // 1440

// ---- workspace layout (floats) ----
#define WS_INST  0       // [512 blocks][16]  (il*2 + {sum,cnt}) = 8192
#define WS_FOCAL 8192    // [2][256][2] = 1024
#define WS_WH    9216    // [256][2]    = 512
#define WS_TAN   9728    // [32]
#define WS_VAR   9760    // [128]
// total 9888 floats

__device__ __forceinline__ float ftanh(float x) {
    float e = __expf(2.0f * x);
    return 1.0f - 2.0f / (e + 1.0f);
}

__device__ __forceinline__ float wave_reduce(float v) {
    #pragma unroll
    for (int off = 1; off < 64; off <<= 1) v += __shfl_xor(v, off, 64);
    return v;
}

__device__ __forceinline__ float block_reduce(float v, float* sbuf) {
    v = wave_reduce(v);
    int lane = threadIdx.x & 63, wid = threadIdx.x >> 6;
    __syncthreads();
    if (lane == 0) sbuf[wid] = v;
    __syncthreads();
    float r = 0.f;
    if (threadIdx.x == 0) {
        for (int i = 0; i < 4; ++i) r += sbuf[i];
    }
    return r;
}

// ---- AE instance focal: PLANE-SEQUENTIAL sweep ----
// idx: b = idx>>7, grp = (idx>>5)&3 (8 instances), seg = idx&31 (32KB of plane).
// For each il: sweep the 32KB mask segment CONTIGUOUSLY (8 x 4KB block-steps),
// re-reading ae (L2-resident; same-(b,seg) grp-blocks share an XCD: stride 32
// blockIdx => same XCD slot mod 8). Only 2 live accumulators; reduces per il
// amortized over 2048 f4. No barriers in the hot loop.
__device__ __forceinline__ void inst_part(int idx, const float* __restrict__ ae,
                                          const float* __restrict__ masks,
                                          const int* __restrict__ centers,
                                          float* __restrict__ ws,
                                          float* __restrict__ s_part) { // [4][16]
    const int tid = threadIdx.x, lane = tid & 63, w = tid >> 6;
    const int b = idx >> 7, grp = (idx >> 5) & 3, seg = idx & 31;
    const float4* aeb   = (const float4*)ae + (size_t)b * 4 * 65536;
    const float4* mbase = (const float4*)masks + ((size_t)(b * NN + grp * 8) << 16);
    const int segf4 = seg * 2048;     // 2048 f4 = 32KB
    const int* cb = centers + (b * NN + grp * 8) * 2;

    #pragma unroll 1
    for (int il = 0; il < 8; ++il) {
        float cy = (float)cb[il * 2]     * (1.0f / 512.0f);   // wave-uniform
        float cx = (float)cb[il * 2 + 1] * (1.0f / 512.0f);
        const float4* mp = mbase + ((size_t)il << 16) + segf4;
        float sum = 0.f, cnt = 0.f;
        float4 mk = mp[tid];
        #pragma unroll
        for (int it = 0; it < 8; ++it) {
            float4 mk_n;
            if (it < 7) mk_n = mp[(it + 1) * 256 + tid];     // sequential prefetch
            int v = segf4 + it * 256 + tid;
            float4 a0 = aeb[v];
            float4 a1 = aeb[65536 + v];
            float4 a2 = aeb[131072 + v];
            float4 a3 = aeb[196608 + v];
            int pix0 = v * 4;
            float fy  = (float)(pix0 >> 9)  * (1.0f / 512.0f);
            float fx0 = (float)(pix0 & 511) * (1.0f / 512.0f);
            #pragma unroll
            for (int j = 0; j < 4; ++j) {
                float se0 = ftanh((&a0.x)[j]) + fy;
                float se1 = ftanh((&a1.x)[j]) + fx0 + (float)j * (1.0f / 512.0f);
                float sg0 = __expf((&a2.x)[j]);
                float sg1 = __expf((&a3.x)[j]);
                float m  = (&mk.x)[j];                 // exactly 0.0 or 1.0
                float dy = se0 - cy, dx = se1 - cx;
                float s  = fmaf(dx * dx, sg1, dy * dy * sg0);
                float e  = __expf(-s);
                float pc = fminf(fmaxf(e, EPSF), ONE_M_EPS);
                float omp = 1.0f - pc;
                // pos: log(pc)*omp^2 ; neg: log(omp)*pc^2 (neg_w==1, binary mask)
                float A = (m != 0.f) ? pc : omp;
                float B = 1.0f - A;
                sum = fmaf(__logf(A), B * B, sum);
                cnt += m;
            }
            mk = mk_n;
        }
        float r0 = wave_reduce(sum);
        float r1 = wave_reduce(cnt);
        if (lane == 0) {
            s_part[w * 16 + il * 2 + 0] = r0;
            s_part[w * 16 + il * 2 + 1] = r1;
        }
    }
    __syncthreads();
    if (tid < 16) {
        float s = s_part[tid] + s_part[16 + tid] + s_part[32 + tid] + s_part[48 + tid];
        ws[WS_INST + idx * 16 + tid] = s;
    }
}

// ---- cls/kp focal: idx = t*256 + blk, 4 iters ----
__device__ __forceinline__ void focal_part(int idx, const float* __restrict__ cls_out,
                                           const float* __restrict__ cls_mask,
                                           const float* __restrict__ kp_out,
                                           const float* __restrict__ kp_mask,
                                           float* __restrict__ ws, float* sbuf) {
    int t = idx >> 8, blk = idx & 255;
    const float4* po = (const float4*)(t == 0 ? cls_out : kp_out);
    const float4* pm = (const float4*)(t == 0 ? cls_mask : kp_mask);
    float sum = 0.f, cnt = 0.f;
    #pragma unroll
    for (int it = 0; it < 4; ++it) {
        int i = blk * 256 + threadIdx.x + it * 65536;
        float4 xo = po[i], xm = pm[i];
        #pragma unroll
        for (int j = 0; j < 4; ++j) {
            float x = (&xo.x)[j], gt = (&xm.x)[j];
            float p = 1.0f / (1.0f + __expf(-x));
            p = fminf(fmaxf(p, EPSF), ONE_M_EPS);
            float omp = 1.0f - p;
            float pos_t = __logf(p) * omp * omp;
            float og = 1.0f - gt;
            float negw = og * og; negw *= negw;
            float neg_t = __logf(omp) * p * p * negw;
            bool ispos = (gt == 1.0f);
            sum += ispos ? pos_t : neg_t;
            cnt += ispos ? 1.0f : 0.0f;
        }
    }
    float r0 = block_reduce(sum, sbuf);
    float r1 = block_reduce(cnt, sbuf);
    if (threadIdx.x == 0) {
        ws[WS_FOCAL + idx * 2 + 0] = r0;
        ws[WS_FOCAL + idx * 2 + 1] = r1;
    }
}

__device__ __forceinline__ void wh_part(int blk, const float* __restrict__ o,
                                        const float* __restrict__ tg,
                                        const float* __restrict__ m,
                                        float* __restrict__ ws, float* sbuf) {
    const float4* po  = (const float4*)o;
    const float4* pt  = (const float4*)tg;
    const float4* pmk = (const float4*)m;
    float sl = 0.f, ms = 0.f;
    #pragma unroll
    for (int it = 0; it < 8; ++it) {
        int i = blk * 256 + threadIdx.x + it * 65536;
        float4 a = po[i], b = pt[i], c = pmk[i];
        #pragma unroll
        for (int j = 0; j < 4; ++j) {
            float mm = (&c.x)[j];
            float d  = (&a.x)[j] * mm - (&b.x)[j] * mm;
            float ad = fabsf(d);
            sl += (ad < 1.0f) ? 0.5f * d * d : (ad - 0.5f);
            ms += mm;
        }
    }
    float r0 = block_reduce(sl, sbuf);
    float r1 = block_reduce(ms, sbuf);
    if (threadIdx.x == 0) {
        ws[WS_WH + blk * 2 + 0] = r0;
        ws[WS_WH + blk * 2 + 1] = r1;
    }
}

__device__ __forceinline__ void tan_part(int idx, const float* __restrict__ tan_out,
                                         const float* __restrict__ normals,
                                         const int* __restrict__ pts,
                                         float* __restrict__ ws, float* sbuf) {
    int b = idx >> 3, seg = idx & 7;
    float s = 0.f;
    for (int p = seg * 1024 + threadIdx.x; p < seg * 1024 + 1024; p += 256) {
        int base = (b * PP + p) * 2;
        int py = pts[base], px = pts[base + 1];
        int pix = py * WIDTH + px;
        float t0 = tan_out[b * 2 * HW + pix];
        float t1 = tan_out[b * 2 * HW + HW + pix];
        float inv = 1.0f / fmaxf(sqrtf(t0 * t0 + t1 * t1), EPSF);
        float n0 = normals[base], n1 = normals[base + 1];
        s += 1.0f - (n0 * t0 + n1 * t1) * inv;
    }
    float r = block_reduce(s, sbuf);
    if (threadIdx.x == 0) ws[WS_TAN + idx] = r;
}

__device__ __forceinline__ void var_part(int idx, const float* __restrict__ ae,
                                         const int* __restrict__ centers,
                                         const int* __restrict__ kps,
                                         float* __restrict__ ws, float* smem) {
    int n = idx & 31, b = idx >> 5;
    float* cy = smem, *cx = smem + 32, *sbuf = smem + 64;
    if (threadIdx.x < NN) {
        int cb = (b * NN + threadIdx.x) * 2;
        cy[threadIdx.x] = centers[cb]     * (1.0f / 512.0f);
        cx[threadIdx.x] = centers[cb + 1] * (1.0f / 512.0f);
    }
    __syncthreads();
    int k = threadIdx.x;
    int kb = ((b * NN + n) * KK + k) * 2;
    int ky = kps[kb], kx = kps[kb + 1];
    int pix = ky * WIDTH + kx;
    const float* aeb = ae + (size_t)b * 4 * HW;
    float se0 = ftanh(aeb[pix])      + ky * (1.0f / 512.0f);
    float se1 = ftanh(aeb[HW + pix]) + kx * (1.0f / 512.0f);
    float sg0 = __expf(aeb[2 * HW + pix]);
    float sg1 = __expf(aeb[3 * HW + pix]);
    float own = 0.f, mx = -1e30f;
    #pragma unroll
    for (int m = 0; m < NN; ++m) {
        float d0 = se0 - cy[m], d1 = se1 - cx[m];
        float dist = __expf(-(d0 * d0 * sg0 + d1 * d1 * sg1));
        mx = fmaxf(mx, dist);
        if (m == n) own = dist;
    }
    float r = block_reduce(fabsf(own - mx), sbuf);
    if (threadIdx.x == 0) ws[WS_VAR + b * NN + n] = r;
}

// ---- the mega kernel: one dispatch for all partials ----
__global__ void __launch_bounds__(256)
k_mega(const float* __restrict__ cls_out, const float* __restrict__ wh_out,
       const float* __restrict__ kp_out,  const float* __restrict__ ae_out,
       const float* __restrict__ tan_out, const float* __restrict__ cls_mask,
       const float* __restrict__ wh_target, const float* __restrict__ wh_mask,
       const float* __restrict__ kp_mask, const float* __restrict__ ae_masks,
       const float* __restrict__ tan_normals,
       const int* __restrict__ centers, const int* __restrict__ kps,
       const int* __restrict__ tan_points, float* __restrict__ ws) {
    __shared__ float smem[256];
    int bid = blockIdx.x;
    if (bid < NBLK_INST) {
        inst_part(bid, ae_out, ae_masks, centers, ws, smem);
    } else if (bid < OFF_FOCAL) {
        wh_part(bid - OFF_WH, wh_out, wh_target, wh_mask, ws, smem);
    } else if (bid < OFF_TAN) {
        focal_part(bid - OFF_FOCAL, cls_out, cls_mask, kp_out, kp_mask, ws, smem);
    } else if (bid < OFF_VAR) {
        tan_part(bid - OFF_TAN, tan_out, tan_normals, tan_points, ws, smem);
    } else {
        var_part(bid - OFF_VAR, ae_out, centers, kps, ws, smem);
    }
}

// ---- finalize: 1 block ----
__global__ void __launch_bounds__(256)
k_final(const float* __restrict__ ws, float* __restrict__ out) {
    __shared__ float sbuf[4];
    int tid = threadIdx.x;
    float ae_v = 0.f;
    if (tid < 128) {   // tid = b*32 + n ; n = grp*8 + i
        int b = tid >> 5, n = tid & 31, grp = n >> 3, i = n & 7;
        const float* base = ws + WS_INST + ((b * 4 + grp) * 32) * 16 + i * 2;
        float sum = 0.f, cnt = 0.f;
        #pragma unroll 8
        for (int seg = 0; seg < 32; ++seg) { sum += base[seg * 16]; cnt += base[seg * 16 + 1]; }
        // where(np>0, -(pos+neg)/max(np,1), -neg) == -sum/max(np,1)  (np==0 => pos==0)
        ae_v = -sum / fmaxf(cnt, 1.0f) + ws[WS_VAR + tid];
    }
    float ae_sum = block_reduce(ae_v, sbuf);

    float cls_sum = block_reduce(ws[WS_FOCAL + tid * 2], sbuf);
    float cls_cnt = block_reduce(ws[WS_FOCAL + tid * 2 + 1], sbuf);
    float kp_sum  = block_reduce(ws[WS_FOCAL + 512 + tid * 2], sbuf);
    float kp_cnt  = block_reduce(ws[WS_FOCAL + 512 + tid * 2 + 1], sbuf);
    float wh_sl   = block_reduce(ws[WS_WH + tid * 2], sbuf);
    float wh_ms   = block_reduce(ws[WS_WH + tid * 2 + 1], sbuf);
    float tan_sum = block_reduce(tid < 32 ? ws[WS_TAN + tid] : 0.f, sbuf);

    if (tid == 0) {
        float l_cls = -cls_sum / fmaxf(cls_cnt, 1.0f);
        float l_kp  = -kp_sum  / fmaxf(kp_cnt,  1.0f);
        float l_wh  = 0.1f * wh_sl / (wh_ms + 1e-4f);
        float l_ae  = ae_sum / (float)(NN * BB);
        float l_tan = tan_sum / (float)(PP * BB);
        out[0] = l_cls + l_wh + l_kp + l_ae + l_tan;
    }
}

extern "C" void kernel_launch(void* const* d_in, const int* in_sizes, int n_in,
                              void* d_out, int out_size, void* d_ws, size_t ws_size,
                              hipStream_t stream) {
    const float* cls_out     = (const float*)d_in[0];
    const float* wh_out      = (const float*)d_in[1];
    const float* kp_out      = (const float*)d_in[2];
    const float* ae_out      = (const float*)d_in[3];
    const float* tan_out     = (const float*)d_in[4];
    const float* cls_mask    = (const float*)d_in[5];
    const float* wh_target   = (const float*)d_in[6];
    const float* wh_mask     = (const float*)d_in[7];
    const float* kp_mask     = (const float*)d_in[8];
    const float* ae_masks    = (const float*)d_in[9];
    const float* tan_normals = (const float*)d_in[10];
    // d_in[11] = xym: analytic (y/512, x/512)
    const int* centers    = (const int*)d_in[12];
    const int* kps        = (const int*)d_in[13];
    const int* tan_points = (const int*)d_in[14];
    float* ws  = (float*)d_ws;
    float* out = (float*)d_out;

    k_mega<<<NBLK_TOTAL, 256, 0, stream>>>(cls_out, wh_out, kp_out, ae_out, tan_out,
                                           cls_mask, wh_target, wh_mask, kp_mask,
                                           ae_masks, tan_normals, centers, kps,
                                           tan_points, ws);
    k_final<<<1, 256, 0, stream>>>(ws, out);
}